// Round 10
// baseline (232.745 us; speedup 1.0000x reference)
//
#include <hip/hip_runtime.h>
#include <hip/hip_bf16.h>
#include <stdint.h>

#define DEV __device__ __forceinline__

typedef __attribute__((ext_vector_type(8))) short bf16x8;
typedef __attribute__((ext_vector_type(4))) short bf16x4;
typedef __attribute__((ext_vector_type(4))) float f32x4;
typedef __attribute__((ext_vector_type(16))) float f32x16;
typedef unsigned short u16;

// ---- async global->LDS, 16B per lane. lds dest must be wave-uniform base. ----
DEV void gload_lds16(const void* g, void* l) {
    typedef const __attribute__((address_space(1))) unsigned int* gp_t;
    typedef __attribute__((address_space(3))) unsigned int* lp_t;
    __builtin_amdgcn_global_load_lds((gp_t)(uintptr_t)g, (lp_t)(uint32_t)(uintptr_t)l, 16, 0, 0);
}

DEV u16 f2bf(float x) {
    union { __hip_bfloat16 h; u16 u; } c;
    c.h = __float2bfloat16(x);
    return c.u;
}
// packed f32x2 -> bf16x2 (v_cvt_pk_bf16_f32 path)
DEV unsigned pack2bf(float a, float b) {
    union { __hip_bfloat162 h2; unsigned u; } cv;
    cv.h2 = __float22bfloat162_rn(make_float2(a, b));
    return cv.u;
}
DEV float bflo(unsigned u) { union { unsigned u; float f; } c; c.u = u << 16; return c.f; }
DEV float bfhi(unsigned u) { union { unsigned u; float f; } c; c.u = u & 0xffff0000u; return c.f; }

// ============================ cast fp32 -> bf16 ============================
__global__ void cast_kernel(const float* __restrict__ src, u16* __restrict__ dst, int n8) {
    int stride = gridDim.x * blockDim.x;
    for (int i = blockIdx.x * blockDim.x + threadIdx.x; i < n8; i += stride) {
        const float4* s = (const float4*)src + (size_t)i * 2;
        float4 a = s[0], b = s[1];
        union { u16 u[8]; uint4 v; } o;
        o.u[0] = f2bf(a.x); o.u[1] = f2bf(a.y); o.u[2] = f2bf(a.z); o.u[3] = f2bf(a.w);
        o.u[4] = f2bf(b.x); o.u[5] = f2bf(b.y); o.u[6] = f2bf(b.z); o.u[7] = f2bf(b.w);
        *((uint4*)dst + i) = o.v;
    }
}

// ============================ projection GEMM ==============================
DEV void gemm_body(const u16* A, const u16* Bw, const float* bias, int bias_row,
                   u16* out, int out_pitch)
{
    __shared__ char smA[16384];
    __shared__ char smB[16384];
    const int lane = threadIdx.x & 63;
    const int w    = threadIdx.x >> 6;
    const int wr   = w >> 1, wc = w & 1;
    const int l15  = lane & 15, lg = lane >> 4;

    f32x4 acc[4][4] = {};
    const char* ag = (const char*)A;
    const char* bg = (const char*)Bw;

    for (int kt = 0; kt < 4; ++kt) {
        __syncthreads();
        #pragma unroll
        for (int c = 0; c < 8; ++c) {
            int ch    = w * 8 + c;
            int loc   = ch & 15;
            int p     = loc * 1024 + lane * 16;
            int row   = p >> 7;
            int inner = (p & 127) ^ ((row & 7) << 4);
            const char* src = (ch < 16 ? ag : bg) + row * 512 + kt * 128 + inner;
            char* dst = (ch < 16 ? smA : smB) + loc * 1024;
            gload_lds16(src, dst);
        }
        __syncthreads();
        #pragma unroll
        for (int ks = 0; ks < 2; ++ks) {
            bf16x8 af[4], bfr[4];
            #pragma unroll
            for (int mi = 0; mi < 4; ++mi) {
                int row = wr * 64 + mi * 16 + l15;
                af[mi] = *(const bf16x8*)(smA + ((row * 128 + ks * 64 + lg * 16) ^ ((row & 7) << 4)));
            }
            #pragma unroll
            for (int ni = 0; ni < 4; ++ni) {
                int row = wc * 64 + ni * 16 + l15;
                bfr[ni] = *(const bf16x8*)(smB + ((row * 128 + ks * 64 + lg * 16) ^ ((row & 7) << 4)));
            }
            #pragma unroll
            for (int mi = 0; mi < 4; ++mi)
                #pragma unroll
                for (int ni = 0; ni < 4; ++ni)
                    acc[mi][ni] = __builtin_amdgcn_mfma_f32_16x16x32_bf16(af[mi], bfr[ni], acc[mi][ni], 0, 0, 0);
        }
    }
    #pragma unroll
    for (int mi = 0; mi < 4; ++mi) {
        #pragma unroll
        for (int ni = 0; ni < 4; ++ni) {
            int n_l  = wc * 64 + ni * 16 + l15;
            float bn = bias_row ? 0.f : bias[n_l];
            #pragma unroll
            for (int r = 0; r < 4; ++r) {
                int row  = wr * 64 + mi * 16 + lg * 4 + r;
                float bb = bias_row ? bias[row] : bn;
                out[(size_t)row * out_pitch + n_l] = f2bf(acc[mi][ni][r] + bb);
            }
        }
    }
}

__global__ __launch_bounds__(256) void proj_qk_kernel(
    const u16* xb, const u16* wqb, const u16* wkb,
    const float* bq, const float* bk, u16* Q, u16* K)
{
    int n0 = blockIdx.x * 128;
    int m0 = blockIdx.y * 128;
    bool isK = n0 >= 256;
    int  nl  = n0 & 255;
    gemm_body(xb + (size_t)m0 * 256, (isK ? wkb : wqb) + (size_t)nl * 256,
              (isK ? bk : bq) + nl, 0,
              (isK ? K : Q) + (size_t)m0 * 256 + nl, 256);
}

__global__ __launch_bounds__(256) void proj_v_kernel(
    const u16* wvb, const u16* xb, const float* bv, u16* Vt)
{
    int n0 = blockIdx.x * 128;
    int m0 = blockIdx.y * 128;
    gemm_body(wvb + (size_t)m0 * 256, xb + (size_t)n0 * 256, bv + m0, 1,
              Vt + (size_t)m0 * 32768 + n0, 32768);
}

// ============================ fused attention ==============================
// W=32 q-rows/wave (halves LDS bytes/FLOP vs W=16 -> LDS-pipe floor ~40us).
// 4 waves x 32 q = 128 q/block; kv-split x2 -> 512 blocks = 2 blocks/CU.
// KVBLK=32 double-buffered: K [32 kv][512B] ^(kv<<4) swizzle (conflict-free,
// folded into 16 loop-invariant addr VGPRs); V pair-packed [128 dp][128B]
// with 16B-slot swizzle ^(dp&7) (2-way = free), staged via pre-permuted
// global sources. QK = 16x mfma_32x32x16; PV = 32x mfma_32x32x8 whose
// B-operand == QK C-fragment slice (zero shuffles, zero P traffic).
__global__ __launch_bounds__(256, 2) void attn_kernel(
    const u16* __restrict__ Q, const u16* __restrict__ K,
    const u16* __restrict__ Vt, float* __restrict__ out,
    u16* __restrict__ p1, float2* __restrict__ ml)
{
    __shared__ char sm[65536];
    // K tile sel: sm + sel*16384          [32 kv][512B], byte ^= (kv&31)<<4
    // V tile sel: sm + 32768 + sel*16384  [128 dp][8 x 16B slots], slot ^= dp&7

    const int lane = threadIdx.x & 63;
    const int w    = threadIdx.x >> 6;
    const int l31  = lane & 31;
    const int g    = lane >> 5;

    // XCD batch-confinement: XCD (lin&7) serves batches {2x,2x+1} -> L2-resident
    const int lin  = blockIdx.x;
    const int b    = (lin & 7) * 2 + ((lin >> 3) & 1);
    const int half = (lin >> 4) & 1;
    const int qt   = lin >> 5;                    // 0..15
    const size_t tokbase = (size_t)b * 2048;
    const int q0w  = qt * 128 + w * 32;           // this wave's 32 q-rows
    const int kvh  = half * 1024;

    // Q fragments (B-operand of QK): lane holds Q[q0w+l31][ks*16 + g*8 + j]
    bf16x8 qf[16];
    {
        const char* qrow = (const char*)(Q + (tokbase + q0w + l31) * 256);
        #pragma unroll
        for (int ks = 0; ks < 16; ++ks)
            qf[ks] = *(const bf16x8*)(qrow + ks * 32 + g * 16);
    }

    // ---- staging offsets (per-lane invariant; uniform per-tile base bump)
    uint32_t gK[4], gV[4];
    #pragma unroll
    for (int j = 0; j < 4; ++j) {
        int c  = w * 4 + j;
        int kv = c * 2 + g;
        gK[j] = (uint32_t)kv * 512 + ((uint32_t)(l31 * 16) ^ (kv << 4));
    }
    #pragma unroll
    for (int j = 0; j < 4; ++j) {
        int c  = w * 4 + j;
        int dp = c * 8 + (lane >> 3);
        int e  = (lane & 7) ^ ((lane >> 3) & 7);
        int d  = dp * 2 + (e >> 2);
        int u  = e & 3;
        gV[j] = (uint32_t)d * 65536 + u * 16;
    }
    const char* Kg = (const char*)K + (tokbase + kvh) * 512;
    const char* Vg = (const char*)Vt + (tokbase + kvh) * 2;

    auto stage = [&](int t, int sel) {
        const char* kb = Kg + (size_t)t * 16384;
        const char* vb = Vg + (size_t)t * 64;
        char* kl = sm + sel * 16384 + w * 4096;
        char* vl = sm + 32768 + sel * 16384 + w * 4096;
        #pragma unroll
        for (int j = 0; j < 4; ++j) gload_lds16(kb + gK[j], kl + j * 1024);
        #pragma unroll
        for (int j = 0; j < 4; ++j) gload_lds16(vb + gV[j], vl + j * 1024);
    };

    // ---- loop-invariant LDS read addresses
    int kaddr[16];
    {
        const int kb0 = l31 * 512 + ((g ^ (l31 & 1)) << 4);
        const int kx  = l31 >> 1;
        #pragma unroll
        for (int ks = 0; ks < 16; ++ks)
            kaddr[ks] = kb0 + (((ks ^ kx) & 15) << 5);
    }
    int vbase[4];
    {
        const int vb0 = 32768 + (l31 >> 1) * 128 + g * 8;
        const int h3  = (l31 >> 1) & 7;
        const int lo4 = (l31 & 1) << 2;
        #pragma unroll
        for (int u = 0; u < 4; ++u)
            vbase[u] = vb0 + (((lo4 | u) ^ h3) << 4);
    }

    f32x16 acc[8] = {};     // O^T: acc[dt][r] = O[d=dt*32+(r&3)+8*(r>>2)+4g][q=l31]
    float m_run  = -1e30f;
    float l_lane = 0.f;     // per-lane partial; reduced in epilogue
    const float C = 0.09016844005556021f;   // (1/16)*log2(e)

    stage(0, 0);
    __syncthreads();

    #pragma unroll 2
    for (int t = 0; t < 32; ++t) {
        const int sel = t & 1;
        if (t < 31) stage(t + 1, sel ^ 1);   // in flight across whole compute

        const char* kp = sm + sel * 16384;
        const char* vp = sm + sel * 16384;

        // ---- S^T = K * Q^T (32kv x 32q), 2 accumulation chains
        f32x16 sa = {}, sb = {};
        #pragma unroll
        for (int ks = 0; ks < 8; ++ks) {
            bf16x8 kf = *(const bf16x8*)(kp + kaddr[ks]);
            sa = __builtin_amdgcn_mfma_f32_32x32x16_bf16(kf, qf[ks], sa, 0, 0, 0);
        }
        #pragma unroll
        for (int ks = 8; ks < 16; ++ks) {
            bf16x8 kf = *(const bf16x8*)(kp + kaddr[ks]);
            sb = __builtin_amdgcn_mfma_f32_32x32x16_bf16(kf, qf[ks], sb, 0, 0, 0);
        }
        f32x16 st = sa + sb;

        // ---- online softmax, shuffle-free fast path (row = lanes {l, l^32})
        float m0 = fmaxf(fmaxf(st[0], st[1]),   fmaxf(st[2], st[3]));
        float m1 = fmaxf(fmaxf(st[4], st[5]),   fmaxf(st[6], st[7]));
        float m2 = fmaxf(fmaxf(st[8], st[9]),   fmaxf(st[10], st[11]));
        float m3 = fmaxf(fmaxf(st[12], st[13]), fmaxf(st[14], st[15]));
        float lmax = fmaxf(fmaxf(m0, m1), fmaxf(m2, m3));

        if (__any(lmax > m_run + 16.f)) {   // trips ~once; rescale rare
            float rmax = fmaxf(lmax, __shfl_xor(lmax, 32, 64));
            float m_new = fmaxf(m_run, rmax);
            float rs = exp2f((m_run - m_new) * C);
            #pragma unroll
            for (int dt = 0; dt < 8; ++dt) acc[dt] *= rs;
            l_lane *= rs;
            m_run = m_new;
        }
        // P = exp2((S - m_run)*C) bounded by exp2(16C) = e (bf16-safe)

        const float mc = m_run * C;
        float sum = 0.f;
        #pragma unroll
        for (int i = 0; i < 16; ++i) {
            float e = exp2f(st[i] * C - mc);
            st[i] = e;
            sum += e;
        }
        l_lane += sum;

        // ---- P fragments: B-operand of mfma_32x32x8 == st slice (no exchange!)
        union { unsigned u2[2]; bf16x4 v; } pb[4];
        #pragma unroll
        for (int u = 0; u < 4; ++u) {
            pb[u].u2[0] = pack2bf(st[u * 4 + 0], st[u * 4 + 1]);
            pb[u].u2[1] = pack2bf(st[u * 4 + 2], st[u * 4 + 3]);
        }

        // ---- PV: acc[dt] += V(d-rows, kvblk u) * P  (8 independent chains)
        #pragma unroll
        for (int u = 0; u < 4; ++u) {
            #pragma unroll
            for (int dt = 0; dt < 8; ++dt) {
                bf16x4 vf = *(const bf16x4*)(vp + vbase[u] + dt * 2048);
                asm("v_mfma_f32_32x32x8_bf16 %0, %1, %2, %0"
                    : "+v"(acc[dt]) : "v"(vf), "v"(pb[u].v));
            }
        }

        __syncthreads();
    }

    // ---- deferred denominator reduce (row pair = lanes {l31, l31+32})
    float l_row = l_lane + __shfl_xor(l_lane, 32, 64);
    if (g == 0)
        ml[half * 32768 + (int)tokbase + q0w + l31] = make_float2(m_run, l_row);

    // ---- epilogue: write UNNORMALIZED partial, transpose via per-wave LDS
    float* ow = (float*)(sm + w * 8448);   // [32 q][66 f32]
    #pragma unroll
    for (int p = 0; p < 4; ++p) {
        #pragma unroll
        for (int dt2 = 0; dt2 < 2; ++dt2) {
            const int dt = p * 2 + dt2;
            #pragma unroll
            for (int r = 0; r < 16; ++r) {
                int dl = dt2 * 32 + (r & 3) + 8 * (r >> 2) + 4 * g;
                ow[l31 * 66 + dl] = acc[dt][r];
            }
        }
        const int qr = (lane >> 4) * 8 + (lane >> 4);  // placeholder removed below
        (void)qr;
        #pragma unroll
        for (int it = 0; it < 8; ++it) {
            int row = it * 4 + (lane >> 4);
            int dc  = (lane & 15) * 4;
            float2 lo = *(const float2*)(ow + row * 66 + dc);
            float2 hi = *(const float2*)(ow + row * 66 + dc + 2);
            if (half == 0) {
                float4 v; v.x = lo.x; v.y = lo.y; v.z = hi.x; v.w = hi.y;
                *(float4*)(out + (tokbase + q0w + row) * 256 + p * 64 + dc) = v;
            } else {
                uint2 pk2 = make_uint2(pack2bf(lo.x, lo.y), pack2bf(hi.x, hi.y));
                *(uint2*)(p1 + (tokbase + q0w + row) * 256 + p * 64 + dc) = pk2;
            }
        }
    }
}

// ============================ combine partials =============================
__global__ __launch_bounds__(256) void combine_kernel(
    float* __restrict__ out, const u16* __restrict__ p1,
    const float2* __restrict__ ml)
{
    const float C = 0.09016844005556021f;
    int idx = blockIdx.x * 256 + threadIdx.x;   // 1,048,576 threads
    int q = idx >> 5;                            // 0..32767 (b*2048 + row)
    int c = idx & 31;                            // 8-float chunk of d
    float2 h0 = ml[q];
    float2 h1 = ml[32768 + q];
    float M  = fmaxf(h0.x, h1.x);
    float k0 = exp2f((h0.x - M) * C);
    float k1 = exp2f((h1.x - M) * C);
    float inv = 1.f / (h0.y * k0 + h1.y * k1);
    k0 *= inv; k1 *= inv;
    size_t off = (size_t)q * 256 + c * 8;
    float4 a0 = *(const float4*)(out + off);
    float4 a1 = *(const float4*)(out + off + 4);
    uint2 u0 = *(const uint2*)(p1 + off);
    uint2 u1 = *(const uint2*)(p1 + off + 4);
    float4 r0, r1;
    r0.x = a0.x * k0 + bflo(u0.x) * k1;
    r0.y = a0.y * k0 + bfhi(u0.x) * k1;
    r0.z = a0.z * k0 + bflo(u0.y) * k1;
    r0.w = a0.w * k0 + bfhi(u0.y) * k1;
    r1.x = a1.x * k0 + bflo(u1.x) * k1;
    r1.y = a1.y * k0 + bfhi(u1.x) * k1;
    r1.z = a1.z * k0 + bflo(u1.y) * k1;
    r1.w = a1.w * k0 + bfhi(u1.y) * k1;
    *(float4*)(out + off)     = r0;
    *(float4*)(out + off + 4) = r1;
}

// ================================ launch ===================================
extern "C" void kernel_launch(void* const* d_in, const int* in_sizes, int n_in,
                              void* d_out, int out_size, void* d_ws, size_t ws_size,
                              hipStream_t stream) {
    (void)in_sizes; (void)n_in; (void)out_size; (void)ws_size;
    const float* x  = (const float*)d_in[0];
    const float* Wq = (const float*)d_in[1];
    const float* bq = (const float*)d_in[2];
    const float* Wk = (const float*)d_in[3];
    const float* bk = (const float*)d_in[4];
    const float* Wv = (const float*)d_in[5];
    const float* bv = (const float*)d_in[6];
    float* out = (float*)d_out;

    char* ws = (char*)d_ws;
    u16* xb  = (u16*)(ws);                  // reused as p1 (bf16 partial) by attn
    u16* wqb = (u16*)(ws + 16777216);
    u16* wkb = (u16*)(ws + 16908288);
    u16* wvb = (u16*)(ws + 17039360);
    u16* Qb  = (u16*)(ws + 17170432);
    u16* Kb  = (u16*)(ws + 33947648);
    u16* Vtb = (u16*)(ws + 50724864);
    float2* ml = (float2*)(ws + 67502080);  // [2 halves][32768 rows] float2

    cast_kernel<<<2048, 256, 0, stream>>>(x,  xb,  1048576);
    cast_kernel<<<64,   256, 0, stream>>>(Wq, wqb, 8192);
    cast_kernel<<<64,   256, 0, stream>>>(Wk, wkb, 8192);
    cast_kernel<<<64,   256, 0, stream>>>(Wv, wvb, 8192);

    proj_qk_kernel<<<dim3(4, 256), 256, 0, stream>>>(xb, wqb, wkb, bq, bk, Qb, Kb);
    proj_v_kernel<<<dim3(256, 2), 256, 0, stream>>>(wvb, xb, bv, Vtb);

    attn_kernel<<<512, 256, 0, stream>>>(Qb, Kb, Vtb, out, xb, ml);
    combine_kernel<<<4096, 256, 0, stream>>>(out, xb, ml);
}

// Round 11
// 190.263 us; speedup vs baseline: 1.2233x; 1.2233x over previous
//
#include <hip/hip_runtime.h>
#include <hip/hip_bf16.h>
#include <stdint.h>

#define DEV __device__ __forceinline__

typedef __attribute__((ext_vector_type(8))) short bf16x8;
typedef __attribute__((ext_vector_type(4))) short bf16x4;
typedef __attribute__((ext_vector_type(4))) float f32x4;
typedef unsigned short u16;

// ---- async global->LDS, 16B per lane. lds dest must be wave-uniform base. ----
DEV void gload_lds16(const void* g, void* l) {
    typedef const __attribute__((address_space(1))) unsigned int* gp_t;
    typedef __attribute__((address_space(3))) unsigned int* lp_t;
    __builtin_amdgcn_global_load_lds((gp_t)(uintptr_t)g, (lp_t)(uint32_t)(uintptr_t)l, 16, 0, 0);
}

DEV u16 f2bf(float x) {
    union { __hip_bfloat16 h; u16 u; } c;
    c.h = __float2bfloat16(x);
    return c.u;
}
// packed f32x2 -> bf16x2 (v_cvt_pk_bf16_f32 path)
DEV unsigned pack2bf(float a, float b) {
    union { __hip_bfloat162 h2; unsigned u; } cv;
    cv.h2 = __float22bfloat162_rn(make_float2(a, b));
    return cv.u;
}
DEV float bflo(unsigned u) { union { unsigned u; float f; } c; c.u = u << 16; return c.f; }
DEV float bfhi(unsigned u) { union { unsigned u; float f; } c; c.u = u & 0xffff0000u; return c.f; }

// Fragment-order global layouts (written by proj, consumed linearly by attn):
// Kfrag: [kv-tile16][ks 0..7][lane 0..63][8 bf16]   lane=(kv&15)|(((k>>3)&3)<<4), e=k&7, ks=k>>5
// Vfrag: [kv-tile16][dt 0..15][lane 0..63][4 bf16]  lane=(d&15)|(((kv>>2)&3)<<4), j=kv&3, dt=d>>4
DEV size_t kidx(int kv, int k) {
    return ((size_t)((kv >> 4) * 8 + (k >> 5)) << 9)
         + (((kv & 15) | (((k >> 3) & 3) << 4)) << 3)
         + (k & 7);
}
DEV size_t vidx(int d, int kv) {
    return ((size_t)((kv >> 4) * 16 + (d >> 4)) << 8)
         + (((d & 15) | (((kv >> 2) & 3) << 4)) << 2)
         + (kv & 3);
}

// ============================ cast fp32 -> bf16 ============================
__global__ void cast_kernel(const float* __restrict__ src, u16* __restrict__ dst, int n8) {
    int stride = gridDim.x * blockDim.x;
    for (int i = blockIdx.x * blockDim.x + threadIdx.x; i < n8; i += stride) {
        const float4* s = (const float4*)src + (size_t)i * 2;
        float4 a = s[0], b = s[1];
        union { u16 u[8]; uint4 v; } o;
        o.u[0] = f2bf(a.x); o.u[1] = f2bf(a.y); o.u[2] = f2bf(a.z); o.u[3] = f2bf(a.w);
        o.u[4] = f2bf(b.x); o.u[5] = f2bf(b.y); o.u[6] = f2bf(b.z); o.u[7] = f2bf(b.w);
        *((uint4*)dst + i) = o.v;
    }
}

// ============================ projection GEMM ==============================
// MODE 0: Q row-major out[gr*256+gc], bias[gc]
// MODE 1: Kfrag out[kidx(gr,gc)],     bias[gc]
// MODE 2: Vfrag out[vidx(gr,gc)],     bias[gr]   (gr=d, gc=token)
template <int MODE>
DEV void gemm_body(const u16* A, const u16* Bw, const float* bias,
                   u16* out, int m0, int n0)
{
    __shared__ char smA[16384];
    __shared__ char smB[16384];
    const int lane = threadIdx.x & 63;
    const int w    = threadIdx.x >> 6;
    const int wr   = w >> 1, wc = w & 1;
    const int l15  = lane & 15, lg = lane >> 4;

    f32x4 acc[4][4] = {};
    const char* ag = (const char*)A;
    const char* bg = (const char*)Bw;

    for (int kt = 0; kt < 4; ++kt) {
        __syncthreads();
        #pragma unroll
        for (int c = 0; c < 8; ++c) {
            int ch    = w * 8 + c;
            int loc   = ch & 15;
            int p     = loc * 1024 + lane * 16;
            int row   = p >> 7;
            int inner = (p & 127) ^ ((row & 7) << 4);
            const char* src = (ch < 16 ? ag : bg) + row * 512 + kt * 128 + inner;
            char* dst = (ch < 16 ? smA : smB) + loc * 1024;
            gload_lds16(src, dst);
        }
        __syncthreads();
        #pragma unroll
        for (int ks = 0; ks < 2; ++ks) {
            bf16x8 af[4], bfr[4];
            #pragma unroll
            for (int mi = 0; mi < 4; ++mi) {
                int row = wr * 64 + mi * 16 + l15;
                af[mi] = *(const bf16x8*)(smA + ((row * 128 + ks * 64 + lg * 16) ^ ((row & 7) << 4)));
            }
            #pragma unroll
            for (int ni = 0; ni < 4; ++ni) {
                int row = wc * 64 + ni * 16 + l15;
                bfr[ni] = *(const bf16x8*)(smB + ((row * 128 + ks * 64 + lg * 16) ^ ((row & 7) << 4)));
            }
            #pragma unroll
            for (int mi = 0; mi < 4; ++mi)
                #pragma unroll
                for (int ni = 0; ni < 4; ++ni)
                    acc[mi][ni] = __builtin_amdgcn_mfma_f32_16x16x32_bf16(af[mi], bfr[ni], acc[mi][ni], 0, 0, 0);
        }
    }
    #pragma unroll
    for (int mi = 0; mi < 4; ++mi) {
        #pragma unroll
        for (int ni = 0; ni < 4; ++ni) {
            int gc = n0 + wc * 64 + ni * 16 + l15;
            float bc = (MODE == 2) ? 0.f : bias[gc];
            #pragma unroll
            for (int r = 0; r < 4; ++r) {
                int gr = m0 + wr * 64 + mi * 16 + lg * 4 + r;
                float bb = (MODE == 2) ? bias[gr] : bc;
                u16 val = f2bf(acc[mi][ni][r] + bb);
                if (MODE == 0)      out[(size_t)gr * 256 + gc] = val;
                else if (MODE == 1) out[kidx(gr, gc)] = val;
                else                out[vidx(gr, gc)] = val;
            }
        }
    }
}

__global__ __launch_bounds__(256) void proj_qk_kernel(
    const u16* xb, const u16* wqb, const u16* wkb,
    const float* bq, const float* bk, u16* Q, u16* Kf)
{
    int n0 = blockIdx.x * 128;   // 0..511: [0,256)=Q cols, [256,512)=K cols
    int m0 = blockIdx.y * 128;   // token tile
    int nl = n0 & 255;
    if (n0 < 256)
        gemm_body<0>(xb + (size_t)m0 * 256, wqb + (size_t)nl * 256, bq, Q,  m0, nl);
    else
        gemm_body<1>(xb + (size_t)m0 * 256, wkb + (size_t)nl * 256, bk, Kf, m0, nl);
}

__global__ __launch_bounds__(256) void proj_v_kernel(
    const u16* wvb, const u16* xb, const float* bv, u16* Vf)
{
    int n0 = blockIdx.x * 128;   // token tile
    int m0 = blockIdx.y * 128;   // d tile (0 or 128)
    gemm_body<2>(wvb + (size_t)m0 * 256, xb + (size_t)n0 * 256, bv, Vf, m0, n0);
}

// ============================ fused attention ==============================
// W=16 q/wave, 4 waves = 64 q/block; kv-split x2 -> 1024 blocks = 4 blocks/CU
// (16 waves/CU). KVBLK=16 double-buffered, 32KB LDS. K/V arrive in fragment
// order from global (linear gload_lds, contiguous & coalesced); LDS reads are
// base + lane*16 + immediate -> conflict-free, zero addressing VALU.
// QK = 8x mfma_16x16x32; PV = 16x mfma_16x16x16 (B == QK C-frag, no shuffle).
__global__ __launch_bounds__(256, 4) void attn_kernel(
    const u16* __restrict__ Q, const u16* __restrict__ Kf,
    const u16* __restrict__ Vf, float* __restrict__ out,
    u16* __restrict__ p1, float2* __restrict__ ml)
{
    __shared__ char sm[32768];
    // buffer sel: K @ sel*16384 (8KB: [ks 0..7][lane][16B]),
    //             V @ sel*16384+8192 (8KB: [dt 0..15][lane][8B])

    const int lane = threadIdx.x & 63;
    const int w    = threadIdx.x >> 6;
    const int l15  = lane & 15;
    const int lg   = lane >> 4;

    // XCD batch-confinement: XCD (lin&7) serves batches {2x,2x+1} -> L2-resident
    const int lin  = blockIdx.x;
    const int b    = (lin & 7) * 2 + ((lin >> 3) & 1);
    const int half = (lin >> 4) & 1;
    const int qt   = lin >> 5;                    // 0..31
    const size_t tokbase = (size_t)b * 2048;
    const int q0w  = qt * 64 + w * 16;

    // Q fragments (B-operand of QK x32): lane holds Q[q0w+l15][ks*32+lg*8+j]
    bf16x8 qf[8];
    {
        const char* qrow = (const char*)(Q + (tokbase + q0w + l15) * 256);
        #pragma unroll
        for (int ks = 0; ks < 8; ++ks)
            qf[ks] = *(const bf16x8*)(qrow + ks * 64 + lg * 16);
    }

    // staging: pure linear copy, 4 gload_lds per wave per tile
    const char* Kgb = (const char*)Kf + ((tokbase + half * 1024) >> 4) * 8192;
    const char* Vgb = (const char*)Vf + ((tokbase + half * 1024) >> 4) * 8192;
    const uint32_t so = (uint32_t)(w * 2048 + lane * 16);

    auto stage = [&](int t, int sel) {
        const char* kg = Kgb + (size_t)t * 8192 + so;
        const char* vg = Vgb + (size_t)t * 8192 + so;
        char* kl = sm + sel * 16384 + w * 2048;
        char* vl = kl + 8192;
        gload_lds16(kg,        kl);
        gload_lds16(kg + 1024, kl + 1024);
        gload_lds16(vg,        vl);
        gload_lds16(vg + 1024, vl + 1024);
    };

    f32x4 acc[16] = {};     // O^T: acc[dt][r] = O[d=dt*16+lg*4+r][q=l15]
    float m_run  = -1e30f;
    float l_lane = 0.f;     // per-lane partial; reduced in epilogue
    const float C = 0.09016844005556021f;   // (1/16)*log2(e)

    stage(0, 0);
    __syncthreads();

    #pragma unroll 2
    for (int t = 0; t < 64; ++t) {
        const int sel = t & 1;
        if (t < 63) stage(t + 1, sel ^ 1);   // in flight across whole compute

        const char* kp = sm + sel * 16384 + lane * 16;
        const char* vp = sm + sel * 16384 + 8192 + lane * 8;

        // ---- S^T = K * Q^T (16 kv x 16 q), 2 accumulation chains
        f32x4 sa = {}, sb = {};
        #pragma unroll
        for (int ks = 0; ks < 4; ++ks) {
            bf16x8 kf = *(const bf16x8*)(kp + ks * 1024);
            sa = __builtin_amdgcn_mfma_f32_16x16x32_bf16(kf, qf[ks], sa, 0, 0, 0);
        }
        #pragma unroll
        for (int ks = 4; ks < 8; ++ks) {
            bf16x8 kf = *(const bf16x8*)(kp + ks * 1024);
            sb = __builtin_amdgcn_mfma_f32_16x16x32_bf16(kf, qf[ks], sb, 0, 0, 0);
        }
        f32x4 st = sa + sb;   // st[r] = S[q=l15][kv = lg*4 + r]

        // ---- online softmax, shuffle-free fast path
        float lmax = fmaxf(fmaxf(st[0], st[1]), fmaxf(st[2], st[3]));
        if (__any(lmax > m_run + 16.f)) {   // rare after first tile
            float rmax = lmax;
            rmax = fmaxf(rmax, __shfl_xor(rmax, 16, 64));
            rmax = fmaxf(rmax, __shfl_xor(rmax, 32, 64));
            float m_new = fmaxf(m_run, rmax);
            float rs = exp2f((m_run - m_new) * C);
            #pragma unroll
            for (int dt = 0; dt < 16; ++dt) acc[dt] *= rs;
            l_lane *= rs;
            m_run = m_new;
        }
        // P = exp2((S - m_run)*C) bounded by exp2(16C) = e (bf16-safe)
        const float mc = m_run * C;
        float e0 = exp2f(st[0] * C - mc);
        float e1 = exp2f(st[1] * C - mc);
        float e2 = exp2f(st[2] * C - mc);
        float e3 = exp2f(st[3] * C - mc);
        l_lane += (e0 + e1) + (e2 + e3);

        // ---- P fragment: B-operand of mfma_16x16x16 == QK C-frag (no exchange)
        union { unsigned u2[2]; bf16x4 v; } pf;
        pf.u2[0] = pack2bf(e0, e1);
        pf.u2[1] = pack2bf(e2, e3);

        // ---- PV: acc[dt] += Vfrag(dt) * P  (16 independent chains)
        #pragma unroll
        for (int dt = 0; dt < 16; ++dt) {
            bf16x4 vf = *(const bf16x4*)(vp + dt * 512);
            asm("v_mfma_f32_16x16x16_bf16 %0, %1, %2, %0"
                : "+v"(acc[dt]) : "v"(vf), "v"(pf.v));
        }

        __syncthreads();   // stage loads were in flight the whole iteration
    }

    // ---- row denominator (lanes {l15, ^16, ^32, ^48} share a q-row)
    float l_row = l_lane;
    l_row += __shfl_xor(l_row, 16, 64);
    l_row += __shfl_xor(l_row, 32, 64);
    if (lg == 0)
        ml[half * 32768 + (int)tokbase + q0w + l15] = make_float2(m_run, l_row);

    // ---- epilogue: write UNNORMALIZED partial (transpose via per-wave LDS)
    float* ow = (float*)(sm + w * 4352);   // [16 q][68 f32]
    #pragma unroll
    for (int p = 0; p < 4; ++p) {
        #pragma unroll
        for (int d2 = 0; d2 < 4; ++d2) {
            const int dt = p * 4 + d2;
            #pragma unroll
            for (int r = 0; r < 4; ++r)
                ow[l15 * 68 + d2 * 16 + lg * 4 + r] = acc[dt][r];
        }
        const int row = lane >> 2;
        const int c0  = (lane & 3) * 16;
        if (half == 0) {
            #pragma unroll
            for (int i = 0; i < 4; ++i) {
                float4 v = *(const float4*)(ow + row * 68 + c0 + i * 4);
                *(float4*)(out + (tokbase + q0w + row) * 256 + p * 64 + c0 + i * 4) = v;
            }
        } else {
            #pragma unroll
            for (int i = 0; i < 4; ++i) {
                float4 v = *(const float4*)(ow + row * 68 + c0 + i * 4);
                uint2 pk2 = make_uint2(pack2bf(v.x, v.y), pack2bf(v.z, v.w));
                *(uint2*)(p1 + (tokbase + q0w + row) * 256 + p * 64 + c0 + i * 4) = pk2;
            }
        }
    }
}

// ============================ combine partials =============================
__global__ __launch_bounds__(256) void combine_kernel(
    float* __restrict__ out, const u16* __restrict__ p1,
    const float2* __restrict__ ml)
{
    const float C = 0.09016844005556021f;
    int idx = blockIdx.x * 256 + threadIdx.x;   // 1,048,576 threads
    int q = idx >> 5;                            // 0..32767 (b*2048 + row)
    int c = idx & 31;                            // 8-float chunk of d
    float2 h0 = ml[q];
    float2 h1 = ml[32768 + q];
    float M  = fmaxf(h0.x, h1.x);
    float k0 = exp2f((h0.x - M) * C);
    float k1 = exp2f((h1.x - M) * C);
    float inv = 1.f / (h0.y * k0 + h1.y * k1);
    k0 *= inv; k1 *= inv;
    size_t off = (size_t)q * 256 + c * 8;
    float4 a0 = *(const float4*)(out + off);
    float4 a1 = *(const float4*)(out + off + 4);
    uint2 u0 = *(const uint2*)(p1 + off);
    uint2 u1 = *(const uint2*)(p1 + off + 4);
    float4 r0, r1;
    r0.x = a0.x * k0 + bflo(u0.x) * k1;
    r0.y = a0.y * k0 + bfhi(u0.x) * k1;
    r0.z = a0.z * k0 + bflo(u0.y) * k1;
    r0.w = a0.w * k0 + bfhi(u0.y) * k1;
    r1.x = a1.x * k0 + bflo(u1.x) * k1;
    r1.y = a1.y * k0 + bfhi(u1.x) * k1;
    r1.z = a1.z * k0 + bflo(u1.y) * k1;
    r1.w = a1.w * k0 + bfhi(u1.y) * k1;
    *(float4*)(out + off)     = r0;
    *(float4*)(out + off + 4) = r1;
}

// ================================ launch ===================================
extern "C" void kernel_launch(void* const* d_in, const int* in_sizes, int n_in,
                              void* d_out, int out_size, void* d_ws, size_t ws_size,
                              hipStream_t stream) {
    (void)in_sizes; (void)n_in; (void)out_size; (void)ws_size;
    const float* x  = (const float*)d_in[0];
    const float* Wq = (const float*)d_in[1];
    const float* bq = (const float*)d_in[2];
    const float* Wk = (const float*)d_in[3];
    const float* bk = (const float*)d_in[4];
    const float* Wv = (const float*)d_in[5];
    const float* bv = (const float*)d_in[6];
    float* out = (float*)d_out;

    char* ws = (char*)d_ws;
    u16* xb  = (u16*)(ws);                  // reused as p1 (bf16 partial) by attn
    u16* wqb = (u16*)(ws + 16777216);
    u16* wkb = (u16*)(ws + 16908288);
    u16* wvb = (u16*)(ws + 17039360);
    u16* Qb  = (u16*)(ws + 17170432);
    u16* Kfr = (u16*)(ws + 33947648);       // K fragment-order, 16MB
    u16* Vfr = (u16*)(ws + 50724864);       // V fragment-order, 16MB
    float2* ml = (float2*)(ws + 67502080);  // [2 halves][32768 rows] float2

    cast_kernel<<<2048, 256, 0, stream>>>(x,  xb,  1048576);
    cast_kernel<<<64,   256, 0, stream>>>(Wq, wqb, 8192);
    cast_kernel<<<64,   256, 0, stream>>>(Wk, wkb, 8192);
    cast_kernel<<<64,   256, 0, stream>>>(Wv, wvb, 8192);

    proj_qk_kernel<<<dim3(4, 256), 256, 0, stream>>>(xb, wqb, wkb, bq, bk, Qb, Kfr);
    proj_v_kernel<<<dim3(256, 2), 256, 0, stream>>>(wvb, xb, bv, Vfr);

    attn_kernel<<<1024, 256, 0, stream>>>(Qb, Kfr, Vfr, out, xb, ml);
    combine_kernel<<<4096, 256, 0, stream>>>(out, xb, ml);
}

// Round 12
// 166.168 us; speedup vs baseline: 1.4007x; 1.1450x over previous
//
#include <hip/hip_runtime.h>
#include <hip/hip_bf16.h>
#include <stdint.h>

#define DEV __device__ __forceinline__

typedef __attribute__((ext_vector_type(8))) short bf16x8;
typedef __attribute__((ext_vector_type(4))) short bf16x4;
typedef __attribute__((ext_vector_type(4))) float f32x4;
typedef __attribute__((ext_vector_type(16))) float f32x16;
typedef unsigned short u16;

// ---- async global->LDS, 16B per lane. lds dest must be wave-uniform base. ----
DEV void gload_lds16(const void* g, void* l) {
    typedef const __attribute__((address_space(1))) unsigned int* gp_t;
    typedef __attribute__((address_space(3))) unsigned int* lp_t;
    __builtin_amdgcn_global_load_lds((gp_t)(uintptr_t)g, (lp_t)(uint32_t)(uintptr_t)l, 16, 0, 0);
}

DEV u16 f2bf(float x) {
    union { __hip_bfloat16 h; u16 u; } c;
    c.h = __float2bfloat16(x);
    return c.u;
}
// packed f32x2 -> bf16x2 (v_cvt_pk_bf16_f32 path)
DEV unsigned pack2bf(float a, float b) {
    union { __hip_bfloat162 h2; unsigned u; } cv;
    cv.h2 = __float22bfloat162_rn(make_float2(a, b));
    return cv.u;
}
DEV float bflo(unsigned u) { union { unsigned u; float f; } c; c.u = u << 16; return c.f; }
DEV float bfhi(unsigned u) { union { unsigned u; float f; } c; c.u = u & 0xffff0000u; return c.f; }

// Fragment-order global layouts for W=32 attention (written by proj):
// Kfrag (QK A-operand, mfma_32x32x16): per kv-tile32, per ks in [0,16):
//   elem = tile*8192 + ks*512 + (g*32 + (kv&31))*8 + e,  k = ks*16 + g*8 + e
// Vfrag (PV A-operand, mfma_32x32x8): per kv-tile32, u in [0,4), dt in [0,8):
//   elem = tile*8192 + u*2048 + dt*256 + (g*32 + (d&31))*4 + j, kv = u*8+g*4+j
DEV size_t kidx(int kv, int k) {
    return ((size_t)(kv >> 5) * 8192) + ((k >> 4) * 512)
         + (((((k >> 3) & 1) << 5) | (kv & 31)) << 3) + (k & 7);
}
DEV size_t vidx(int d, int kv) {
    return ((size_t)(kv >> 5) * 8192) + (((kv >> 3) & 3) * 2048) + ((d >> 5) * 256)
         + (((((kv >> 2) & 1) << 5) | (d & 31)) << 2) + (kv & 3);
}

// ============================ cast fp32 -> bf16 ============================
__global__ void cast_kernel(const float* __restrict__ src, u16* __restrict__ dst, int n8) {
    int stride = gridDim.x * blockDim.x;
    for (int i = blockIdx.x * blockDim.x + threadIdx.x; i < n8; i += stride) {
        const float4* s = (const float4*)src + (size_t)i * 2;
        float4 a = s[0], b = s[1];
        union { u16 u[8]; uint4 v; } o;
        o.u[0] = f2bf(a.x); o.u[1] = f2bf(a.y); o.u[2] = f2bf(a.z); o.u[3] = f2bf(a.w);
        o.u[4] = f2bf(b.x); o.u[5] = f2bf(b.y); o.u[6] = f2bf(b.z); o.u[7] = f2bf(b.w);
        *((uint4*)dst + i) = o.v;
    }
}

// ============================ projection GEMM ==============================
// MODE 0: Q row-major out[gr*256+gc], bias[gc]
// MODE 1: Kfrag out[kidx(gr,gc)],     bias[gc]   (gr=token/kv, gc=channel)
// MODE 2: Vfrag out[vidx(gr,gc)],     bias[gr]   (gr=d, gc=token/kv)
template <int MODE>
DEV void gemm_body(const u16* A, const u16* Bw, const float* bias,
                   u16* out, int m0, int n0)
{
    __shared__ char smA[16384];
    __shared__ char smB[16384];
    const int lane = threadIdx.x & 63;
    const int w    = threadIdx.x >> 6;
    const int wr   = w >> 1, wc = w & 1;
    const int l15  = lane & 15, lg = lane >> 4;

    f32x4 acc[4][4] = {};
    const char* ag = (const char*)A;
    const char* bg = (const char*)Bw;

    for (int kt = 0; kt < 4; ++kt) {
        __syncthreads();
        #pragma unroll
        for (int c = 0; c < 8; ++c) {
            int ch    = w * 8 + c;
            int loc   = ch & 15;
            int p     = loc * 1024 + lane * 16;
            int row   = p >> 7;
            int inner = (p & 127) ^ ((row & 7) << 4);
            const char* src = (ch < 16 ? ag : bg) + row * 512 + kt * 128 + inner;
            char* dst = (ch < 16 ? smA : smB) + loc * 1024;
            gload_lds16(src, dst);
        }
        __syncthreads();
        #pragma unroll
        for (int ks = 0; ks < 2; ++ks) {
            bf16x8 af[4], bfr[4];
            #pragma unroll
            for (int mi = 0; mi < 4; ++mi) {
                int row = wr * 64 + mi * 16 + l15;
                af[mi] = *(const bf16x8*)(smA + ((row * 128 + ks * 64 + lg * 16) ^ ((row & 7) << 4)));
            }
            #pragma unroll
            for (int ni = 0; ni < 4; ++ni) {
                int row = wc * 64 + ni * 16 + l15;
                bfr[ni] = *(const bf16x8*)(smB + ((row * 128 + ks * 64 + lg * 16) ^ ((row & 7) << 4)));
            }
            #pragma unroll
            for (int mi = 0; mi < 4; ++mi)
                #pragma unroll
                for (int ni = 0; ni < 4; ++ni)
                    acc[mi][ni] = __builtin_amdgcn_mfma_f32_16x16x32_bf16(af[mi], bfr[ni], acc[mi][ni], 0, 0, 0);
        }
    }
    #pragma unroll
    for (int mi = 0; mi < 4; ++mi) {
        #pragma unroll
        for (int ni = 0; ni < 4; ++ni) {
            int gc = n0 + wc * 64 + ni * 16 + l15;
            float bc = (MODE == 2) ? 0.f : bias[gc];
            #pragma unroll
            for (int r = 0; r < 4; ++r) {
                int gr = m0 + wr * 64 + mi * 16 + lg * 4 + r;
                float bb = (MODE == 2) ? bias[gr] : bc;
                u16 val = f2bf(acc[mi][ni][r] + bb);
                if (MODE == 0)      out[(size_t)gr * 256 + gc] = val;
                else if (MODE == 1) out[kidx(gr, gc)] = val;
                else                out[vidx(gr, gc)] = val;
            }
        }
    }
}

__global__ __launch_bounds__(256) void proj_qk_kernel(
    const u16* xb, const u16* wqb, const u16* wkb,
    const float* bq, const float* bk, u16* Q, u16* Kf)
{
    int n0 = blockIdx.x * 128;   // 0..511: [0,256)=Q cols, [256,512)=K cols
    int m0 = blockIdx.y * 128;   // token tile
    int nl = n0 & 255;
    if (n0 < 256)
        gemm_body<0>(xb + (size_t)m0 * 256, wqb + (size_t)nl * 256, bq, Q,  m0, nl);
    else
        gemm_body<1>(xb + (size_t)m0 * 256, wkb + (size_t)nl * 256, bk, Kf, m0, nl);
}

__global__ __launch_bounds__(256) void proj_v_kernel(
    const u16* wvb, const u16* xb, const float* bv, u16* Vf)
{
    int n0 = blockIdx.x * 128;   // token tile
    int m0 = blockIdx.y * 128;   // d tile (0 or 128)
    gemm_body<2>(wvb + (size_t)m0 * 256, xb + (size_t)n0 * 256, bv, Vf, m0, n0);
}

// ============================ fused attention ==============================
// W=32 q/wave (32B LDS per q-kv pair, half of W=16). 4 waves = 128 q/block;
// kv-split x2 -> 512 blocks = 2 blocks/CU. KVBLK=32 double-buffered, 64KB LDS.
// K/V arrive in fragment order (linear coalesced gload_lds); LDS reads are
// lane*16/8 + immediate -> conflict-free, zero addressing VALU.
// QK = 16x mfma_32x32x16; PV = 32x mfma_32x32x8 (B == QK C-frag slice).
__global__ __launch_bounds__(256, 2) void attn_kernel(
    const u16* __restrict__ Q, const u16* __restrict__ Kf,
    const u16* __restrict__ Vf, float* __restrict__ out,
    u16* __restrict__ p1, float2* __restrict__ ml)
{
    __shared__ char sm[65536];
    // buffer sel: K @ sel*32768 (16KB: [ks 0..15][lane][16B]),
    //             V @ sel*32768+16384 (16KB: [u 0..3][dt 0..7][lane][8B])

    const int lane = threadIdx.x & 63;
    const int w    = threadIdx.x >> 6;
    const int l31  = lane & 31;
    const int g    = lane >> 5;

    // XCD batch-confinement: XCD (lin&7) serves batches {2x,2x+1} -> L2-resident
    const int lin  = blockIdx.x;
    const int b    = (lin & 7) * 2 + ((lin >> 3) & 1);
    const int half = (lin >> 4) & 1;
    const int qt   = lin >> 5;                    // 0..15
    const size_t tokbase = (size_t)b * 2048;
    const int q0w  = qt * 128 + w * 32;           // this wave's 32 q-rows
    const int kvh  = half * 1024;

    // Q fragments (B-operand of QK): lane holds Q[q0w+l31][ks*16 + g*8 + e]
    bf16x8 qf[16];
    {
        const char* qrow = (const char*)(Q + (tokbase + q0w + l31) * 256);
        #pragma unroll
        for (int ks = 0; ks < 16; ++ks)
            qf[ks] = *(const bf16x8*)(qrow + ks * 32 + g * 16);
    }

    // staging: pure linear copy, 8 gload_lds per wave per tile (4 K + 4 V)
    const char* Kgb = (const char*)Kf + (tokbase + kvh) * 512;
    const char* Vgb = (const char*)Vf + (tokbase + kvh) * 512;
    const uint32_t so = (uint32_t)(w * 4096 + lane * 16);

    auto stage = [&](int t, int sel) {
        const char* kg = Kgb + (size_t)t * 16384 + so;
        const char* vg = Vgb + (size_t)t * 16384 + so;
        char* kl = sm + sel * 32768 + w * 4096;
        char* vl = kl + 16384;
        #pragma unroll
        for (int j = 0; j < 4; ++j) gload_lds16(kg + j * 1024, kl + j * 1024);
        #pragma unroll
        for (int j = 0; j < 4; ++j) gload_lds16(vg + j * 1024, vl + j * 1024);
    };

    f32x16 acc[8] = {};     // O^T: acc[dt][r] = O[d=dt*32+(r&3)+8*(r>>2)+4g][q=l31]
    float m_run  = -1e30f;
    float l_lane = 0.f;     // per-lane partial; reduced in epilogue
    const float C = 0.09016844005556021f;   // (1/16)*log2(e)

    stage(0, 0);
    __syncthreads();

    for (int t = 0; t < 32; ++t) {
        const int sel = t & 1;
        if (t < 31) stage(t + 1, sel ^ 1);   // in flight across whole compute

        const char* kp = sm + sel * 32768 + lane * 16;
        const char* vp = sm + sel * 32768 + 16384 + lane * 8;

        // ---- S^T = K * Q^T (32 kv x 32 q), 2 accumulation chains
        f32x16 sa = {}, sb = {};
        #pragma unroll
        for (int ks = 0; ks < 8; ++ks) {
            bf16x8 kf = *(const bf16x8*)(kp + ks * 1024);
            sa = __builtin_amdgcn_mfma_f32_32x32x16_bf16(kf, qf[ks], sa, 0, 0, 0);
        }
        #pragma unroll
        for (int ks = 8; ks < 16; ++ks) {
            bf16x8 kf = *(const bf16x8*)(kp + ks * 1024);
            sb = __builtin_amdgcn_mfma_f32_32x32x16_bf16(kf, qf[ks], sb, 0, 0, 0);
        }
        f32x16 st = sa + sb;   // st[u*4+j] = S[q=l31][kv = u*8 + g*4 + j]

        // ---- online softmax, shuffle-free fast path (row = lanes {l, l^32})
        float m0 = fmaxf(fmaxf(st[0], st[1]),   fmaxf(st[2], st[3]));
        float m1 = fmaxf(fmaxf(st[4], st[5]),   fmaxf(st[6], st[7]));
        float m2 = fmaxf(fmaxf(st[8], st[9]),   fmaxf(st[10], st[11]));
        float m3 = fmaxf(fmaxf(st[12], st[13]), fmaxf(st[14], st[15]));
        float lmax = fmaxf(fmaxf(m0, m1), fmaxf(m2, m3));

        if (__any(lmax > m_run + 16.f)) {   // rare after first tile
            float rmax = fmaxf(lmax, __shfl_xor(lmax, 32, 64));
            float m_new = fmaxf(m_run, rmax);
            float rs = exp2f((m_run - m_new) * C);
            #pragma unroll
            for (int dt = 0; dt < 8; ++dt) acc[dt] *= rs;
            l_lane *= rs;
            m_run = m_new;
        }
        // P = exp2((S - m_run)*C) bounded by exp2(16C) = e (bf16-safe)

        const float mc = m_run * C;
        float sum = 0.f;
        #pragma unroll
        for (int i = 0; i < 16; ++i) {
            float e = exp2f(st[i] * C - mc);
            st[i] = e;
            sum += e;
        }
        l_lane += sum;

        // ---- P fragments: B-operand of mfma_32x32x8 == st slice (no exchange)
        union { unsigned u2[2]; bf16x4 v; } pb[4];
        #pragma unroll
        for (int u = 0; u < 4; ++u) {
            pb[u].u2[0] = pack2bf(st[u * 4 + 0], st[u * 4 + 1]);
            pb[u].u2[1] = pack2bf(st[u * 4 + 2], st[u * 4 + 3]);
        }

        // ---- PV: acc[dt] += Vfrag(u, dt) * P  (8 independent chains)
        #pragma unroll
        for (int u = 0; u < 4; ++u) {
            #pragma unroll
            for (int dt = 0; dt < 8; ++dt) {
                bf16x4 vf = *(const bf16x4*)(vp + u * 4096 + dt * 512);
                asm("v_mfma_f32_32x32x8_bf16 %0, %1, %2, %0"
                    : "+v"(acc[dt]) : "v"(vf), "v"(pb[u].v));
            }
        }

        __syncthreads();   // stage loads were in flight the whole iteration
    }

    // ---- row denominator (row pair = lanes {l31, l31+32})
    float l_row = l_lane + __shfl_xor(l_lane, 32, 64);
    if (g == 0)
        ml[half * 32768 + (int)tokbase + q0w + l31] = make_float2(m_run, l_row);

    // ---- epilogue: write UNNORMALIZED partial, transpose via per-wave LDS
    float* ow = (float*)(sm + w * 8448);   // [32 q][66 f32]
    #pragma unroll
    for (int p = 0; p < 4; ++p) {
        #pragma unroll
        for (int dt2 = 0; dt2 < 2; ++dt2) {
            const int dt = p * 2 + dt2;
            #pragma unroll
            for (int r = 0; r < 16; ++r) {
                int dl = dt2 * 32 + (r & 3) + 8 * (r >> 2) + 4 * g;
                ow[l31 * 66 + dl] = acc[dt][r];
            }
        }
        #pragma unroll
        for (int it = 0; it < 8; ++it) {
            int row = it * 4 + (lane >> 4);
            int dc  = (lane & 15) * 4;
            float2 lo = *(const float2*)(ow + row * 66 + dc);
            float2 hi = *(const float2*)(ow + row * 66 + dc + 2);
            if (half == 0) {
                float4 v; v.x = lo.x; v.y = lo.y; v.z = hi.x; v.w = hi.y;
                *(float4*)(out + (tokbase + q0w + row) * 256 + p * 64 + dc) = v;
            } else {
                uint2 pk2 = make_uint2(pack2bf(lo.x, lo.y), pack2bf(hi.x, hi.y));
                *(uint2*)(p1 + (tokbase + q0w + row) * 256 + p * 64 + dc) = pk2;
            }
        }
    }
}

// ============================ combine partials =============================
__global__ __launch_bounds__(256) void combine_kernel(
    float* __restrict__ out, const u16* __restrict__ p1,
    const float2* __restrict__ ml)
{
    const float C = 0.09016844005556021f;
    int idx = blockIdx.x * 256 + threadIdx.x;   // 1,048,576 threads
    int q = idx >> 5;                            // 0..32767 (b*2048 + row)
    int c = idx & 31;                            // 8-float chunk of d
    float2 h0 = ml[q];
    float2 h1 = ml[32768 + q];
    float M  = fmaxf(h0.x, h1.x);
    float k0 = exp2f((h0.x - M) * C);
    float k1 = exp2f((h1.x - M) * C);
    float inv = 1.f / (h0.y * k0 + h1.y * k1);
    k0 *= inv; k1 *= inv;
    size_t off = (size_t)q * 256 + c * 8;
    float4 a0 = *(const float4*)(out + off);
    float4 a1 = *(const float4*)(out + off + 4);
    uint2 u0 = *(const uint2*)(p1 + off);
    uint2 u1 = *(const uint2*)(p1 + off + 4);
    float4 r0, r1;
    r0.x = a0.x * k0 + bflo(u0.x) * k1;
    r0.y = a0.y * k0 + bfhi(u0.x) * k1;
    r0.z = a0.z * k0 + bflo(u0.y) * k1;
    r0.w = a0.w * k0 + bfhi(u0.y) * k1;
    r1.x = a1.x * k0 + bflo(u1.x) * k1;
    r1.y = a1.y * k0 + bfhi(u1.x) * k1;
    r1.z = a1.z * k0 + bflo(u1.y) * k1;
    r1.w = a1.w * k0 + bfhi(u1.y) * k1;
    *(float4*)(out + off)     = r0;
    *(float4*)(out + off + 4) = r1;
}

// ================================ launch ===================================
extern "C" void kernel_launch(void* const* d_in, const int* in_sizes, int n_in,
                              void* d_out, int out_size, void* d_ws, size_t ws_size,
                              hipStream_t stream) {
    (void)in_sizes; (void)n_in; (void)out_size; (void)ws_size;
    const float* x  = (const float*)d_in[0];
    const float* Wq = (const float*)d_in[1];
    const float* bq = (const float*)d_in[2];
    const float* Wk = (const float*)d_in[3];
    const float* bk = (const float*)d_in[4];
    const float* Wv = (const float*)d_in[5];
    const float* bv = (const float*)d_in[6];
    float* out = (float*)d_out;

    char* ws = (char*)d_ws;
    u16* xb  = (u16*)(ws);                  // reused as p1 (bf16 partial) by attn
    u16* wqb = (u16*)(ws + 16777216);
    u16* wkb = (u16*)(ws + 16908288);
    u16* wvb = (u16*)(ws + 17039360);
    u16* Qb  = (u16*)(ws + 17170432);
    u16* Kfr = (u16*)(ws + 33947648);       // K fragment-order, 16MB
    u16* Vfr = (u16*)(ws + 50724864);       // V fragment-order, 16MB
    float2* ml = (float2*)(ws + 67502080);  // [2 halves][32768 rows] float2

    cast_kernel<<<2048, 256, 0, stream>>>(x,  xb,  1048576);
    cast_kernel<<<64,   256, 0, stream>>>(Wq, wqb, 8192);
    cast_kernel<<<64,   256, 0, stream>>>(Wk, wkb, 8192);
    cast_kernel<<<64,   256, 0, stream>>>(Wv, wvb, 8192);

    proj_qk_kernel<<<dim3(4, 256), 256, 0, stream>>>(xb, wqb, wkb, bq, bk, Qb, Kfr);
    proj_v_kernel<<<dim3(256, 2), 256, 0, stream>>>(wvb, xb, bv, Vfr);

    attn_kernel<<<512, 256, 0, stream>>>(Qb, Kfr, Vfr, out, xb, ml);
    combine_kernel<<<4096, 256, 0, stream>>>(out, xb, ml);
}

// Round 14
// 148.187 us; speedup vs baseline: 1.5706x; 1.1213x over previous
//
#include <hip/hip_runtime.h>
#include <hip/hip_bf16.h>
#include <stdint.h>

#define DEV __device__ __forceinline__

typedef __attribute__((ext_vector_type(8))) short bf16x8;
typedef __attribute__((ext_vector_type(4))) float f32x4;
typedef __attribute__((ext_vector_type(16))) float f32x16;
typedef unsigned short u16;

// ---- async global->LDS, 16B per lane. lds dest must be wave-uniform base. ----
DEV void gload_lds16(const void* g, void* l) {
    typedef const __attribute__((address_space(1))) unsigned int* gp_t;
    typedef __attribute__((address_space(3))) unsigned int* lp_t;
    __builtin_amdgcn_global_load_lds((gp_t)(uintptr_t)g, (lp_t)(uint32_t)(uintptr_t)l, 16, 0, 0);
}

DEV u16 f2bf(float x) {
    union { __hip_bfloat16 h; u16 u; } c;
    c.h = __float2bfloat16(x);
    return c.u;
}
// packed f32x2 -> bf16x2 (v_cvt_pk_bf16_f32 path)
DEV unsigned pack2bf(float a, float b) {
    union { __hip_bfloat162 h2; unsigned u; } cv;
    cv.h2 = __float22bfloat162_rn(make_float2(a, b));
    return cv.u;
}
DEV float bflo(unsigned u) { union { unsigned u; float f; } c; c.u = u << 16; return c.f; }
DEV float bfhi(unsigned u) { union { unsigned u; float f; } c; c.u = u & 0xffff0000u; return c.f; }

// Fragment-order global layouts for W=32 attention (written by proj).
// All indices below are u16 ELEMENT indices (x2 for bytes):
// Kfrag (QK A-operand, mfma_32x32x16): per kv-tile32, ks in [0,16):
//   elem = tile*8192 + ks*512 + ((((k>>3)&1)<<5 | (kv&31))<<3) + (k&7)
//   -> byte strides: tile 16384, ks 1024, lane 16
// Vfrag (PV A-operand, mfma_32x32x16): per kv-tile32, kv-half h=(kv>>4)&1,
//   dt=d>>5: lane ((kv>>3)&1)<<5 | (d&31) supplies V^T[d][kv], e=kv&7:
//   elem = tile*8192 + h*4096 + dt*512 + (lane<<3) + e
//   -> byte strides: tile 16384, h 8192, dt 1024, lane 16
DEV size_t kidx(int kv, int k) {
    return ((size_t)(kv >> 5) * 8192) + ((k >> 4) * 512)
         + (((((k >> 3) & 1) << 5) | (kv & 31)) << 3) + (k & 7);
}
DEV size_t vidx(int d, int kv) {
    return ((size_t)(kv >> 5) * 8192) + (((kv >> 4) & 1) * 4096) + ((d >> 5) * 512)
         + (((((kv >> 3) & 1) << 5) | (d & 31)) << 3) + (kv & 7);
}

// ===================== cast fp32 -> bf16 (all four inputs) =====================
__global__ void cast_all_kernel(
    const float* __restrict__ x,  const float* __restrict__ wq,
    const float* __restrict__ wk, const float* __restrict__ wv,
    u16* __restrict__ xb, u16* __restrict__ wqb,
    u16* __restrict__ wkb, u16* __restrict__ wvb)
{
    const int total = 1048576 + 3 * 8192;   // groups of 8 floats
    int stride = gridDim.x * blockDim.x;
    for (int i = blockIdx.x * blockDim.x + threadIdx.x; i < total; i += stride) {
        const float* s; u16* d; int off;
        if (i < 1048576) { s = x; d = xb; off = i; }
        else {
            int j = i - 1048576;
            int wsel = j >> 13;
            off = j & 8191;
            s = (wsel == 0) ? wq : (wsel == 1) ? wk : wv;
            d = (wsel == 0) ? wqb : (wsel == 1) ? wkb : wvb;
        }
        const float4* sp = (const float4*)s + (size_t)off * 2;
        float4 a = sp[0], b = sp[1];
        union { u16 u[8]; uint4 v; } o;
        o.u[0] = f2bf(a.x); o.u[1] = f2bf(a.y); o.u[2] = f2bf(a.z); o.u[3] = f2bf(a.w);
        o.u[4] = f2bf(b.x); o.u[5] = f2bf(b.y); o.u[6] = f2bf(b.z); o.u[7] = f2bf(b.w);
        *((uint4*)d + off) = o.v;
    }
}

// ============================ projection GEMM ==============================
// MODE 0: Q row-major out[gr*256+gc], bias[gc]
// MODE 1: Kfrag out[kidx(gr,gc)],     bias[gc]   (gr=token/kv, gc=channel)
// MODE 2: Vfrag out[vidx(gr,gc)],     bias[gr]   (gr=d, gc=token/kv)
template <int MODE>
DEV void gemm_body(const u16* A, const u16* Bw, const float* bias,
                   u16* out, int m0, int n0)
{
    __shared__ char smA[16384];
    __shared__ char smB[16384];
    const int lane = threadIdx.x & 63;
    const int w    = threadIdx.x >> 6;
    const int wr   = w >> 1, wc = w & 1;
    const int l15  = lane & 15, lg = lane >> 4;

    f32x4 acc[4][4] = {};
    const char* ag = (const char*)A;
    const char* bg = (const char*)Bw;

    for (int kt = 0; kt < 4; ++kt) {
        __syncthreads();
        #pragma unroll
        for (int c = 0; c < 8; ++c) {
            int ch    = w * 8 + c;
            int loc   = ch & 15;
            int p     = loc * 1024 + lane * 16;
            int row   = p >> 7;
            int inner = (p & 127) ^ ((row & 7) << 4);
            const char* src = (ch < 16 ? ag : bg) + row * 512 + kt * 128 + inner;
            char* dst = (ch < 16 ? smA : smB) + loc * 1024;
            gload_lds16(src, dst);
        }
        __syncthreads();
        #pragma unroll
        for (int ks = 0; ks < 2; ++ks) {
            bf16x8 af[4], bfr[4];
            #pragma unroll
            for (int mi = 0; mi < 4; ++mi) {
                int row = wr * 64 + mi * 16 + l15;
                af[mi] = *(const bf16x8*)(smA + ((row * 128 + ks * 64 + lg * 16) ^ ((row & 7) << 4)));
            }
            #pragma unroll
            for (int ni = 0; ni < 4; ++ni) {
                int row = wc * 64 + ni * 16 + l15;
                bfr[ni] = *(const bf16x8*)(smB + ((row * 128 + ks * 64 + lg * 16) ^ ((row & 7) << 4)));
            }
            #pragma unroll
            for (int mi = 0; mi < 4; ++mi)
                #pragma unroll
                for (int ni = 0; ni < 4; ++ni)
                    acc[mi][ni] = __builtin_amdgcn_mfma_f32_16x16x32_bf16(af[mi], bfr[ni], acc[mi][ni], 0, 0, 0);
        }
    }
    #pragma unroll
    for (int mi = 0; mi < 4; ++mi) {
        #pragma unroll
        for (int ni = 0; ni < 4; ++ni) {
            int gc = n0 + wc * 64 + ni * 16 + l15;
            float bc = (MODE == 2) ? 0.f : bias[gc];
            #pragma unroll
            for (int r = 0; r < 4; ++r) {
                int gr = m0 + wr * 64 + mi * 16 + lg * 4 + r;
                float bb = (MODE == 2) ? bias[gr] : bc;
                u16 val = f2bf(acc[mi][ni][r] + bb);
                if (MODE == 0)      out[(size_t)gr * 256 + gc] = val;
                else if (MODE == 1) out[kidx(gr, gc)] = val;
                else                out[vidx(gr, gc)] = val;
            }
        }
    }
}

__global__ __launch_bounds__(256) void proj_all_kernel(
    const u16* xb, const u16* wqb, const u16* wkb, const u16* wvb,
    const float* bq, const float* bk, const float* bv,
    u16* Q, u16* Kf, u16* Vf)
{
    int xg = blockIdx.x;             // 0,1: Q  2,3: K  4,5: V d-tiles
    int m0 = blockIdx.y * 128;       // token tile
    if (xg < 2) {
        int nl = xg * 128;
        gemm_body<0>(xb + (size_t)m0 * 256, wqb + (size_t)nl * 256, bq, Q,  m0, nl);
    } else if (xg < 4) {
        int nl = (xg - 2) * 128;
        gemm_body<1>(xb + (size_t)m0 * 256, wkb + (size_t)nl * 256, bk, Kf, m0, nl);
    } else {
        int dm0 = (xg - 4) * 128;
        gemm_body<2>(wvb + (size_t)dm0 * 256, xb + (size_t)m0 * 256, bv, Vf, dm0, m0);
    }
}

// ============================ fused attention ==============================
// W=32 q/wave, 4 waves = 128 q/block; kv-split x2 -> 512 blocks = 2 blocks/CU
// (register-capped: 128 AGPR acc + ~128 VGPR). KVBLK=32 dbuf, 64KB LDS,
// fragment-order K/V (linear coalesced staging, conflict-free LDS reads).
// QK = 16x mfma_32x32x16; PV = 16x mfma_32x32x16 with B-frag built from the
// QK C-frag via one shfl_xor(32) pair exchange per half.
__global__ __launch_bounds__(256, 2) void attn_kernel(
    const u16* __restrict__ Q, const u16* __restrict__ Kf,
    const u16* __restrict__ Vf, float* __restrict__ out,
    u16* __restrict__ p1, float2* __restrict__ ml)
{
    __shared__ char sm[65536];
    // buffer sel: K @ sel*32768 (16KB: [ks 0..15][lane][16B]),
    //             V @ sel*32768+16384 (16KB: [h 0..1][dt 0..7][lane][16B])

    const int lane = threadIdx.x & 63;
    const int w    = threadIdx.x >> 6;
    const int l31  = lane & 31;
    const int g    = lane >> 5;

    // XCD batch-confinement: XCD (lin&7) serves batches {2x,2x+1} -> L2-resident
    const int lin  = blockIdx.x;
    const int b    = (lin & 7) * 2 + ((lin >> 3) & 1);
    const int half = (lin >> 4) & 1;
    const int qt   = lin >> 5;                    // 0..15
    const size_t tokbase = (size_t)b * 2048;
    const int q0w  = qt * 128 + w * 32;           // this wave's 32 q-rows
    const int kvh  = half * 1024;

    // Q fragments (B-operand of QK): lane holds Q[q0w+l31][ks*16 + g*8 + e]
    bf16x8 qf[16];
    {
        const char* qrow = (const char*)(Q + (tokbase + q0w + l31) * 256);
        #pragma unroll
        for (int ks = 0; ks < 16; ++ks)
            qf[ks] = *(const bf16x8*)(qrow + ks * 32 + g * 16);
    }

    // staging: pure linear copy, 8 gload_lds per wave per tile (4 K + 4 V)
    const char* Kgb = (const char*)Kf + (tokbase + kvh) * 512;
    const char* Vgb = (const char*)Vf + (tokbase + kvh) * 512;
    const uint32_t so = (uint32_t)(w * 4096 + lane * 16);

    auto stage = [&](int t, int sel) {
        const char* kg = Kgb + (size_t)t * 16384 + so;
        const char* vg = Vgb + (size_t)t * 16384 + so;
        char* kl = sm + sel * 32768 + w * 4096;
        char* vl = kl + 16384;
        #pragma unroll
        for (int j = 0; j < 4; ++j) gload_lds16(kg + j * 1024, kl + j * 1024);
        #pragma unroll
        for (int j = 0; j < 4; ++j) gload_lds16(vg + j * 1024, vl + j * 1024);
    };

    f32x16 acc[8] = {};     // O^T: acc[dt][r] = O[d=dt*32+(r&3)+8*(r>>2)+4g][q=l31]
    float m_run  = -1e30f;
    float l_lane = 0.f;     // per-lane partial; reduced in epilogue
    const float C = 0.09016844005556021f;   // (1/16)*log2(e)

    stage(0, 0);
    __syncthreads();

    for (int t = 0; t < 32; ++t) {
        const int sel = t & 1;
        if (t < 31) stage(t + 1, sel ^ 1);   // in flight across whole compute

        const char* kp = sm + sel * 32768 + lane * 16;
        const char* vp = sm + sel * 32768 + 16384 + lane * 16;

        // ---- S^T = K * Q^T (32 kv x 32 q), 2 accumulation chains
        f32x16 sa = {}, sb = {};
        #pragma unroll
        for (int ks = 0; ks < 8; ++ks) {
            bf16x8 kf = *(const bf16x8*)(kp + ks * 1024);
            sa = __builtin_amdgcn_mfma_f32_32x32x16_bf16(kf, qf[ks], sa, 0, 0, 0);
        }
        #pragma unroll
        for (int ks = 8; ks < 16; ++ks) {
            bf16x8 kf = *(const bf16x8*)(kp + ks * 1024);
            sb = __builtin_amdgcn_mfma_f32_32x32x16_bf16(kf, qf[ks], sb, 0, 0, 0);
        }
        f32x16 st = sa + sb;   // st[u*4+j] = S^T[kv = u*8 + 4g + j][q = l31]

        // ---- online softmax, shuffle-free fast path (row = lanes {l, l^32})
        float m0 = fmaxf(fmaxf(st[0], st[1]),   fmaxf(st[2], st[3]));
        float m1 = fmaxf(fmaxf(st[4], st[5]),   fmaxf(st[6], st[7]));
        float m2 = fmaxf(fmaxf(st[8], st[9]),   fmaxf(st[10], st[11]));
        float m3 = fmaxf(fmaxf(st[12], st[13]), fmaxf(st[14], st[15]));
        float lmax = fmaxf(fmaxf(m0, m1), fmaxf(m2, m3));

        if (__any(lmax > m_run + 16.f)) {   // rare after first tile
            float rmax = fmaxf(lmax, __shfl_xor(lmax, 32, 64));
            float m_new = fmaxf(m_run, rmax);
            float rs = exp2f((m_run - m_new) * C);
            #pragma unroll
            for (int dt = 0; dt < 8; ++dt) acc[dt] *= rs;
            l_lane *= rs;
            m_run = m_new;
        }
        // P = exp2((S - m_run)*C) bounded by exp2(16C) = e (bf16-safe)

        const float mc = m_run * C;
        float sum = 0.f;
        #pragma unroll
        for (int i = 0; i < 16; ++i) {
            float e = exp2f(st[i] * C - mc);
            st[i] = e;
            sum += e;
        }
        l_lane += sum;

        // ---- pack P: pk{u} = kv pair {8u+4g+2h, +1} at q=l31
        unsigned pk0 = pack2bf(st[0], st[1]),   pk1 = pack2bf(st[2], st[3]);
        unsigned pk2 = pack2bf(st[4], st[5]),   pk3 = pack2bf(st[6], st[7]);
        unsigned pk4 = pack2bf(st[8], st[9]),   pk5 = pack2bf(st[10], st[11]);
        unsigned pk6 = pack2bf(st[12], st[13]), pk7 = pack2bf(st[14], st[15]);

        // ---- exchange to x16 B-frags: lane needs P^T[kv=h*16+g*8+e][q=l31]
        // g=0 sends its u=1,3 pairs; g=1 sends its u=0,2 pairs.
        unsigned s0a = g ? pk0 : pk2,  s0b = g ? pk1 : pk3;
        unsigned s1a = g ? pk4 : pk6,  s1b = g ? pk5 : pk7;
        unsigned r0a = __shfl_xor(s0a, 32, 64);
        unsigned r0b = __shfl_xor(s0b, 32, 64);
        unsigned r1a = __shfl_xor(s1a, 32, 64);
        unsigned r1b = __shfl_xor(s1b, 32, 64);
        union { unsigned u[4]; bf16x8 v; } pB0, pB1;
        pB0.u[0] = g ? r0a : pk0;  pB0.u[1] = g ? r0b : pk1;
        pB0.u[2] = g ? pk2 : r0a;  pB0.u[3] = g ? pk3 : r0b;
        pB1.u[0] = g ? r1a : pk4;  pB1.u[1] = g ? r1b : pk5;
        pB1.u[2] = g ? pk6 : r1a;  pB1.u[3] = g ? pk7 : r1b;

        // ---- PV: acc[dt] += Vfrag(h, dt) * P   (byte strides: h 8192, dt 1024)
        #pragma unroll
        for (int dt = 0; dt < 8; ++dt) {
            bf16x8 v0 = *(const bf16x8*)(vp + dt * 1024);
            acc[dt] = __builtin_amdgcn_mfma_f32_32x32x16_bf16(v0, pB0.v, acc[dt], 0, 0, 0);
        }
        #pragma unroll
        for (int dt = 0; dt < 8; ++dt) {
            bf16x8 v1 = *(const bf16x8*)(vp + 8192 + dt * 1024);
            acc[dt] = __builtin_amdgcn_mfma_f32_32x32x16_bf16(v1, pB1.v, acc[dt], 0, 0, 0);
        }

        __syncthreads();   // stage loads were in flight the whole iteration
    }

    // ---- row denominator (row pair = lanes {l31, l31+32})
    float l_row = l_lane + __shfl_xor(l_lane, 32, 64);
    if (g == 0)
        ml[half * 32768 + (int)tokbase + q0w + l31] = make_float2(m_run, l_row);

    // ---- epilogue: write UNNORMALIZED partial, transpose via per-wave LDS
    float* ow = (float*)(sm + w * 8448);   // [32 q][66 f32]
    #pragma unroll
    for (int p = 0; p < 4; ++p) {
        #pragma unroll
        for (int dt2 = 0; dt2 < 2; ++dt2) {
            const int dt = p * 2 + dt2;
            #pragma unroll
            for (int r = 0; r < 16; ++r) {
                int dl = dt2 * 32 + (r & 3) + 8 * (r >> 2) + 4 * g;
                ow[l31 * 66 + dl] = acc[dt][r];
            }
        }
        #pragma unroll
        for (int it = 0; it < 8; ++it) {
            int row = it * 4 + (lane >> 4);
            int dc  = (lane & 15) * 4;
            float2 lo = *(const float2*)(ow + row * 66 + dc);
            float2 hi = *(const float2*)(ow + row * 66 + dc + 2);
            if (half == 0) {
                float4 v; v.x = lo.x; v.y = lo.y; v.z = hi.x; v.w = hi.y;
                *(float4*)(out + (tokbase + q0w + row) * 256 + p * 64 + dc) = v;
            } else {
                uint2 pk2v = make_uint2(pack2bf(lo.x, lo.y), pack2bf(hi.x, hi.y));
                *(uint2*)(p1 + (tokbase + q0w + row) * 256 + p * 64 + dc) = pk2v;
            }
        }
    }
}

// ============================ combine partials =============================
__global__ __launch_bounds__(256) void combine_kernel(
    float* __restrict__ out, const u16* __restrict__ p1,
    const float2* __restrict__ ml)
{
    const float C = 0.09016844005556021f;
    int idx = blockIdx.x * 256 + threadIdx.x;   // 1,048,576 threads
    int q = idx >> 5;                            // 0..32767 (b*2048 + row)
    int c = idx & 31;                            // 8-float chunk of d
    float2 h0 = ml[q];
    float2 h1 = ml[32768 + q];
    float M  = fmaxf(h0.x, h1.x);
    float k0 = exp2f((h0.x - M) * C);
    float k1 = exp2f((h1.x - M) * C);
    float inv = 1.f / (h0.y * k0 + h1.y * k1);
    k0 *= inv; k1 *= inv;
    size_t off = (size_t)q * 256 + c * 8;
    float4 a0 = *(const float4*)(out + off);
    float4 a1 = *(const float4*)(out + off + 4);
    uint2 u0 = *(const uint2*)(p1 + off);
    uint2 u1 = *(const uint2*)(p1 + off + 4);
    float4 r0, r1;
    r0.x = a0.x * k0 + bflo(u0.x) * k1;
    r0.y = a0.y * k0 + bfhi(u0.x) * k1;
    r0.z = a0.z * k0 + bflo(u0.y) * k1;
    r0.w = a0.w * k0 + bfhi(u0.y) * k1;
    r1.x = a1.x * k0 + bflo(u1.x) * k1;
    r1.y = a1.y * k0 + bfhi(u1.x) * k1;
    r1.z = a1.z * k0 + bflo(u1.y) * k1;
    r1.w = a1.w * k0 + bfhi(u1.y) * k1;
    *(float4*)(out + off)     = r0;
    *(float4*)(out + off + 4) = r1;
}

// ================================ launch ===================================
extern "C" void kernel_launch(void* const* d_in, const int* in_sizes, int n_in,
                              void* d_out, int out_size, void* d_ws, size_t ws_size,
                              hipStream_t stream) {
    (void)in_sizes; (void)n_in; (void)out_size; (void)ws_size;
    const float* x  = (const float*)d_in[0];
    const float* Wq = (const float*)d_in[1];
    const float* bq = (const float*)d_in[2];
    const float* Wk = (const float*)d_in[3];
    const float* bk = (const float*)d_in[4];
    const float* Wv = (const float*)d_in[5];
    const float* bv = (const float*)d_in[6];
    float* out = (float*)d_out;

    char* ws = (char*)d_ws;
    u16* xb  = (u16*)(ws);                  // reused as p1 (bf16 partial) by attn
    u16* wqb = (u16*)(ws + 16777216);
    u16* wkb = (u16*)(ws + 16908288);
    u16* wvb = (u16*)(ws + 17039360);
    u16* Qb  = (u16*)(ws + 17170432);
    u16* Kfr = (u16*)(ws + 33947648);       // K fragment-order, 16MB
    u16* Vfr = (u16*)(ws + 50724864);       // V fragment-order, 16MB
    float2* ml = (float2*)(ws + 67502080);  // [2 halves][32768 rows] float2

    cast_all_kernel<<<2048, 256, 0, stream>>>(x, Wq, Wk, Wv, xb, wqb, wkb, wvb);

    proj_all_kernel<<<dim3(6, 256), 256, 0, stream>>>(
        xb, wqb, wkb, wvb, bq, bk, bv, Qb, Kfr, Vfr);

    attn_kernel<<<512, 256, 0, stream>>>(Qb, Kfr, Vfr, out, xb, ml);
    combine_kernel<<<4096, 256, 0, stream>>>(out, xb, ml);
}